// Round 1
// 334.618 us; speedup vs baseline: 1.1975x; 1.1975x over previous
//
#include <hip/hip_runtime.h>
#include <hip/hip_bf16.h>

// DCNv2 CrossNet on MI355X — fused 3-layer kernel, v5.
// Key change vs v4: BT=32 rows/block (was 64) -> LDS 50.7 KB/block -> 3
// blocks/CU = 24 waves/CU (6 waves/SIMD, was 2). v4 was latency-bound:
// MfmaUtil 6.8%, VALUBusy 10.3%, HBM 13%, Occupancy 23% -> every pipe idle,
// waves stalled on L2 weight-fragment latency with nothing to schedule.
// To fit the 85-VGPR budget of 6 waves/SIMD (__launch_bounds__(512,6)),
// GEMM3 + epilogue are split into two 32-col halves (acc3 64->16 regs).
// Wave decomposition otherwise identical to v4 (N-split, e=wave>>1 etc.),
// only the row-tile count per thread halves (mt_r=2).
// Padded (non-XOR) LDS layouts kept: +8-short pad is conflict-free for both
// b128 A-reads and scalar u16 epilogue ops (v3's XOR swizzle regressed).
//
// Shapes: x[32768,512]; Vs[3,4,64,512]; Cs[3,4,64,64]; Us[3,4,512,64];
//         bias[3,512]; gate_w[512,4].

#define CROSS   3
#define ENUM    4
#define LR      64
#define ELD     256     // ENUM*LR
#define DIM     512
#define BATCH   32768
#define BT      32      // batch rows per block
#define MT      2       // row-tiles (16 rows each) per thread
#define NTHR    512     // 8 waves

#define XL_W    520     // 512 + 8 pad (shorts)
#define Y_W     264     // 256 + 8 pad (shorts)

typedef __bf16 bf16x8 __attribute__((ext_vector_type(8)));
typedef float  f32x4  __attribute__((ext_vector_type(4)));
typedef unsigned short us;
typedef unsigned short us4 __attribute__((ext_vector_type(4)));

__device__ __forceinline__ us f2bf(float f) {
    return __builtin_bit_cast(us, (__bf16)f);
}
__device__ __forceinline__ float bf2f(us b) {
    unsigned int u = ((unsigned int)b) << 16;
    return __builtin_bit_cast(float, u);
}
// fast tanh: (e^2x - 1) / (e^2x + 1); inputs bounded by 0.05-scaled weights.
__device__ __forceinline__ float tanh_fast(float x) {
    float t = __expf(2.f * x);
    return (t - 1.f) * __builtin_amdgcn_rcpf(t + 1.f);
}

#define MFMA(a, b, c) __builtin_amdgcn_mfma_f32_16x16x32_bf16(a, b, c, 0, 0, 0)

// ---------------------------------------------------------------------------
// Swizzle prepass: fp32 weights -> bf16 MFMA-B fragment order
// frag[nt][ks][lane][8]: n = nt*16 + (lane&15), k = ks*32 + (lane>>4)*8 + j.
// ---------------------------------------------------------------------------
__global__ __launch_bounds__(64) void swz_all(
    const float* __restrict__ Vs, const float* __restrict__ Cs,
    const float* __restrict__ Us, const float* __restrict__ gw,
    us* __restrict__ Vf, us* __restrict__ Cf,
    us* __restrict__ Uf, us* __restrict__ Gf)
{
    int b = blockIdx.x;
    int lane = threadIdx.x;
    if (b < 768) {                       // V: [3][16 nt][16 ks]
        int i = b >> 8, t = b & 255;
        int nt = t >> 4, ks = t & 15;
        int n  = nt * 16 + (lane & 15);
        int k0 = ks * 32 + (lane >> 4) * 8;
        const float* src = Vs + (size_t)i * ELD * DIM + (size_t)n * DIM + k0;
        us* dst = Vf + (size_t)i * ELD * DIM
                + ((size_t)(nt * 16 + ks) * 64 + lane) * 8;
        #pragma unroll
        for (int j = 0; j < 8; ++j) dst[j] = f2bf(src[j]);
    } else if (b < 1536) {               // U': [3][32 nt][8 ks], k = e*64+l
        int bb = b - 768;
        int i = bb >> 8, t = bb & 255;
        int nt = t >> 3, ks = t & 7;
        int n  = nt * 16 + (lane & 15);            // d
        int k0 = ks * 32 + (lane >> 4) * 8;        // e*64 + l
        int e = k0 >> 6, l0 = k0 & 63;
        const float* src = Us + (size_t)i * ENUM * DIM * LR
                         + (size_t)e * DIM * LR + (size_t)n * LR + l0;
        us* dst = Uf + (size_t)i * DIM * ELD
                + ((size_t)(nt * 8 + ks) * 64 + lane) * 8;
        #pragma unroll
        for (int j = 0; j < 8; ++j) dst[j] = f2bf(src[j]);
    } else if (b < 1632) {               // C: [3][4 e][4 nt][2 ks]
        int bb = b - 1536;
        int i = bb >> 5, rest = bb & 31;
        int e = rest >> 3, t = rest & 7;
        int nt = t >> 1, ks = t & 1;
        int n  = nt * 16 + (lane & 15);
        int k0 = ks * 32 + (lane >> 4) * 8;
        const float* src = Cs + (((size_t)(i * ENUM + e) * LR + n) * LR) + k0;
        us* dst = Cf + (size_t)i * ENUM * LR * LR
                + ((size_t)((e * 4 + nt) * 2 + ks) * 64 + lane) * 8;
        #pragma unroll
        for (int j = 0; j < 8; ++j) dst[j] = f2bf(src[j]);
    } else {                             // gate: [16 ks], n<4 real, rest 0
        int ks = b - 1632;
        int n  = lane & 15;
        int k0 = ks * 32 + (lane >> 4) * 8;
        us* dst = Gf + ((size_t)ks * 64 + lane) * 8;
        #pragma unroll
        for (int j = 0; j < 8; ++j)
            dst[j] = (n < ENUM) ? f2bf(gw[(size_t)(k0 + j) * ENUM + n]) : (us)0;
    }
}

// ---------------------------------------------------------------------------
// Fused 3-layer kernel. Block: 32 rows, 512 threads (8 waves), 3 blocks/CU.
// Thread element ownership (16x16x32 D-layout, mt in 0..1):
//   row = mt*16 + quad*4 + r,  col(G3) = wave*64 + nt*16 + nl.
// G1: wave owns cols [wave*32,+32) (nt_r=2); wave 0 additionally folds the
// gate GEMM in as one extra B-fragment. G2: expert e = wave>>1, col-half
// h = wave&1. G3: wave owns cols [wave*64,+64) (nt_r=4), processed in two
// 32-col halves so peak VGPR pressure stays under the 85-reg / 6-wave cap.
// ---------------------------------------------------------------------------
__global__ __launch_bounds__(NTHR, 6) void dcn_fused(
    const float* __restrict__ x,
    float* __restrict__ out,
    const us* __restrict__ Vf,
    const us* __restrict__ Cf,
    const us* __restrict__ Uf,
    const us* __restrict__ Gf,
    const float* __restrict__ bias)
{
    __shared__ us xl_s[BT * XL_W];       // x_l master, bf16 (33.3 KB)
    __shared__ us y_s[BT * Y_W];         // Y then z (16.9 KB)
    __shared__ float g_s[BT * ENUM];     // gate scores (0.5 KB)

    const int tid  = threadIdx.x;
    const int wave = tid >> 6, lane = tid & 63;
    const int quad = lane >> 4, nl = lane & 15;
    const int row0 = blockIdx.x * BT;

    // ---- stage x -> xl_s (bf16): 32*128 = 4096 float4s, 8 per thread
    #pragma unroll
    for (int it = 0; it < 8; ++it) {
        int f4 = tid + it * NTHR;            // 0..4095
        int r = f4 >> 7, c4 = f4 & 127;
        float4 v = *reinterpret_cast<const float4*>(
            x + (size_t)(row0 + r) * DIM + c4 * 4);
        us4 p;
        p[0] = f2bf(v.x); p[1] = f2bf(v.y); p[2] = f2bf(v.z); p[3] = f2bf(v.w);
        *reinterpret_cast<us4*>(&xl_s[r * XL_W + c4 * 4]) = p;
    }
    __syncthreads();

    // ---- x0 packed bf16 in regs (thread's ownership elements)
    unsigned int x0p[MT][4][2];
    #pragma unroll
    for (int mt = 0; mt < MT; ++mt)
        #pragma unroll
        for (int nt = 0; nt < 4; ++nt) {
            int rb = mt * 16 + quad * 4;
            int col = wave * 64 + nt * 16 + nl;
            unsigned int b0 = xl_s[(rb + 0) * XL_W + col];
            unsigned int b1 = xl_s[(rb + 1) * XL_W + col];
            unsigned int b2 = xl_s[(rb + 2) * XL_W + col];
            unsigned int b3 = xl_s[(rb + 3) * XL_W + col];
            x0p[mt][nt][0] = b0 | (b1 << 16);
            x0p[mt][nt][1] = b2 | (b3 << 16);
        }

    #pragma unroll 1
    for (int layer = 0; layer < CROSS; ++layer) {
        const us* Vl = Vf + (size_t)layer * ELD * DIM;
        const us* Cl = Cf + (size_t)layer * ENUM * LR * LR;
        const us* Ul = Uf + (size_t)layer * DIM * ELD;
        const float* bl = bias + layer * DIM;

        // ---- GEMM1: Y = tanh(xl @ V^T), wave cols [wave*32,+32); wave 0: gate
        f32x4 acc1[MT][2];
        f32x4 gacc[MT];
        #pragma unroll
        for (int mt = 0; mt < MT; ++mt) {
            gacc[mt] = (f32x4)0.f;
            acc1[mt][0] = (f32x4)0.f;
            acc1[mt][1] = (f32x4)0.f;
        }
        #pragma unroll 4
        for (int ks = 0; ks < 16; ++ks) {
            bf16x8 a[MT];
            #pragma unroll
            for (int mt = 0; mt < MT; ++mt)
                a[mt] = *reinterpret_cast<const bf16x8*>(
                    &xl_s[(mt * 16 + nl) * XL_W + ks * 32 + quad * 8]);
            #pragma unroll
            for (int nt = 0; nt < 2; ++nt) {
                bf16x8 bfr = *reinterpret_cast<const bf16x8*>(
                    &Vl[((size_t)((wave * 2 + nt) * 16 + ks) * 64 + lane) * 8]);
                #pragma unroll
                for (int mt = 0; mt < MT; ++mt)
                    acc1[mt][nt] = MFMA(a[mt], bfr, acc1[mt][nt]);
            }
            if (wave == 0) {
                bf16x8 bg = *reinterpret_cast<const bf16x8*>(
                    &Gf[((size_t)ks * 64 + lane) * 8]);
                #pragma unroll
                for (int mt = 0; mt < MT; ++mt)
                    gacc[mt] = MFMA(a[mt], bg, gacc[mt]);
            }
        }
        #pragma unroll
        for (int mt = 0; mt < MT; ++mt)
            #pragma unroll
            for (int r = 0; r < 4; ++r) {
                int row = mt * 16 + quad * 4 + r;
                #pragma unroll
                for (int nt = 0; nt < 2; ++nt)
                    y_s[row * Y_W + wave * 32 + nt * 16 + nl] =
                        f2bf(tanh_fast(acc1[mt][nt][r]));
            }
        if (wave == 0 && nl < ENUM) {
            #pragma unroll
            for (int mt = 0; mt < MT; ++mt)
                #pragma unroll
                for (int r = 0; r < 4; ++r)
                    g_s[(mt * 16 + quad * 4 + r) * ENUM + nl] = gacc[mt][r];
        }
        __syncthreads();

        // ---- GEMM2: z = g ⊙ tanh(Y_e @ C_e^T). e = wave>>1, half = wave&1.
        const int e = wave >> 1, h = wave & 1;
        f32x4 acc2[MT][2];
        #pragma unroll
        for (int mt = 0; mt < MT; ++mt) {
            acc2[mt][0] = (f32x4)0.f;
            acc2[mt][1] = (f32x4)0.f;
        }
        #pragma unroll
        for (int ks = 0; ks < 2; ++ks) {
            bf16x8 a[MT];
            #pragma unroll
            for (int mt = 0; mt < MT; ++mt)
                a[mt] = *reinterpret_cast<const bf16x8*>(
                    &y_s[(mt * 16 + nl) * Y_W + e * 64 + ks * 32 + quad * 8]);
            #pragma unroll
            for (int nt = 0; nt < 2; ++nt) {
                bf16x8 bfr = *reinterpret_cast<const bf16x8*>(
                    &Cl[((size_t)((e * 4 + h * 2 + nt) * 2 + ks) * 64 + lane) * 8]);
                #pragma unroll
                for (int mt = 0; mt < MT; ++mt)
                    acc2[mt][nt] = MFMA(a[mt], bfr, acc2[mt][nt]);
            }
        }
        __syncthreads();   // all Y reads complete before in-place overwrite
        #pragma unroll
        for (int mt = 0; mt < MT; ++mt)
            #pragma unroll
            for (int r = 0; r < 4; ++r) {
                int row = mt * 16 + quad * 4 + r;
                float gv = g_s[row * ENUM + e];
                #pragma unroll
                for (int nt = 0; nt < 2; ++nt)
                    y_s[row * Y_W + e * 64 + h * 32 + nt * 16 + nl] =
                        f2bf(tanh_fast(acc2[mt][nt][r]) * gv);
            }
        __syncthreads();

        // ---- Gv = sum_e g[row][e]
        float Gv[MT][4];
        #pragma unroll
        for (int mt = 0; mt < MT; ++mt)
            #pragma unroll
            for (int r = 0; r < 4; ++r) {
                int row = mt * 16 + quad * 4 + r;
                f32x4 g4 = *reinterpret_cast<const f32x4*>(&g_s[row * ENUM]);
                Gv[mt][r] = g4[0] + g4[1] + g4[2] + g4[3];
            }

        // ---- GEMM3: core = z @ U'^T, wave cols [wave*64,+64), K=256.
        // Two 32-col halves to keep acc3 at 16 VGPRs (6-wave/SIMD budget).
        #pragma unroll 1
        for (int h3 = 0; h3 < 2; ++h3) {
            float bc[2];
            bc[0] = bl[wave * 64 + h3 * 32 + nl];
            bc[1] = bl[wave * 64 + h3 * 32 + 16 + nl];
            f32x4 acc3[MT][2];
            #pragma unroll
            for (int mt = 0; mt < MT; ++mt) {
                acc3[mt][0] = (f32x4)0.f;
                acc3[mt][1] = (f32x4)0.f;
            }
            #pragma unroll 2
            for (int ks = 0; ks < 8; ++ks) {
                bf16x8 a[MT];
                #pragma unroll
                for (int mt = 0; mt < MT; ++mt)
                    a[mt] = *reinterpret_cast<const bf16x8*>(
                        &y_s[(mt * 16 + nl) * Y_W + ks * 32 + quad * 8]);
                #pragma unroll
                for (int nt = 0; nt < 2; ++nt) {
                    bf16x8 bfr = *reinterpret_cast<const bf16x8*>(
                        &Ul[((size_t)((wave * 4 + h3 * 2 + nt) * 8 + ks) * 64
                             + lane) * 8]);
                    #pragma unroll
                    for (int mt = 0; mt < MT; ++mt)
                        acc3[mt][nt] = MFMA(a[mt], bfr, acc3[mt][nt]);
                }
            }

            // ---- epilogue (this half): xl = xl + x0 * (core + bias*G)
            #pragma unroll
            for (int nt = 0; nt < 2; ++nt) {
                int col = wave * 64 + h3 * 32 + nt * 16 + nl;
                #pragma unroll
                for (int mt = 0; mt < MT; ++mt)
                    #pragma unroll
                    for (int r = 0; r < 4; ++r) {
                        int row = mt * 16 + quad * 4 + r;
                        float x0v = bf2f((us)(
                            x0p[mt][h3 * 2 + nt][r >> 1] >> ((r & 1) * 16)));
                        float xlo = bf2f(xl_s[row * XL_W + col]);
                        float res = xlo
                                  + x0v * (acc3[mt][nt][r] + bc[nt] * Gv[mt][r]);
                        if (layer == CROSS - 1)
                            out[(size_t)(row0 + row) * DIM + col] = res;
                        else
                            xl_s[row * XL_W + col] = f2bf(res);
                    }
            }
        }
        if (layer < CROSS - 1) __syncthreads();
    }
}

// ---------------------------------------------------------------------------
extern "C" void kernel_launch(void* const* d_in, const int* in_sizes, int n_in,
                              void* d_out, int out_size, void* d_ws,
                              size_t ws_size, hipStream_t stream) {
    const float* x      = (const float*)d_in[0];
    const float* Vs     = (const float*)d_in[1];
    const float* Cs     = (const float*)d_in[2];
    const float* Us     = (const float*)d_in[3];
    const float* bias   = (const float*)d_in[4];
    const float* gate_w = (const float*)d_in[5];
    float* out = (float*)d_out;

    us* Vf = (us*)d_ws;                                   // 393216 bf16
    us* Uf = Vf + (size_t)CROSS * ELD * DIM;              // 393216
    us* Cf = Uf + (size_t)CROSS * DIM * ELD;              // 49152
    us* Gf = Cf + (size_t)CROSS * ENUM * LR * LR;         // 8192

    swz_all<<<1648, 64, 0, stream>>>(Vs, Cs, Us, gate_w, Vf, Cf, Uf, Gf);
    dcn_fused<<<BATCH / BT, NTHR, 0, stream>>>(x, out, Vf, Cf, Uf, Gf, bias);
}

// Round 2
// 316.598 us; speedup vs baseline: 1.2656x; 1.0569x over previous
//
#include <hip/hip_runtime.h>
#include <hip/hip_bf16.h>

// DCNv2 CrossNet on MI355X — fused 3-layer kernel, v6.
// Key change vs v5: BT=16 rows/block (was 32), MT=1. LDS 25.3 KB/block ->
// wave-cap-limited 4 blocks/CU = 32 waves/CU = 100% occupancy, and
// grid = 2048 = 256 CU x 4 blocks x exactly 2 rounds (v5 had 1.33 rounds:
// a 75%-occupancy round + a 25% straggler round -> measured 50% occupancy,
// still latency-bound: MfmaUtil 9.3, VALU 15, HBM 16.7).
// __launch_bounds__(512,8) caps VGPRs at 64 (8 waves/SIMD budget); v5
// compiled to 40 VGPRs at MT=2 so MT=1 fits easily.
// Accepted cost: per-fragment weight reuse halves -> L2 weight stream
// ~3.1 GB aggregate (~42 B/cyc/CU at 140 us) — inside the 56 B/cyc share.
// Padded (non-XOR) LDS layouts kept: +8-short pad is conflict-free for both
// b128 A-reads and scalar u16 epilogue ops (v3's XOR swizzle regressed).
//
// Shapes: x[32768,512]; Vs[3,4,64,512]; Cs[3,4,64,64]; Us[3,4,512,64];
//         bias[3,512]; gate_w[512,4].

#define CROSS   3
#define ENUM    4
#define LR      64
#define ELD     256     // ENUM*LR
#define DIM     512
#define BATCH   32768
#define BT      16      // batch rows per block
#define MT      1       // row-tiles (16 rows each) per thread
#define NTHR    512     // 8 waves

#define XL_W    520     // 512 + 8 pad (shorts)
#define Y_W     264     // 256 + 8 pad (shorts)

typedef __bf16 bf16x8 __attribute__((ext_vector_type(8)));
typedef float  f32x4  __attribute__((ext_vector_type(4)));
typedef unsigned short us;
typedef unsigned short us4 __attribute__((ext_vector_type(4)));

__device__ __forceinline__ us f2bf(float f) {
    return __builtin_bit_cast(us, (__bf16)f);
}
__device__ __forceinline__ float bf2f(us b) {
    unsigned int u = ((unsigned int)b) << 16;
    return __builtin_bit_cast(float, u);
}
// fast tanh: (e^2x - 1) / (e^2x + 1); inputs bounded by 0.05-scaled weights.
__device__ __forceinline__ float tanh_fast(float x) {
    float t = __expf(2.f * x);
    return (t - 1.f) * __builtin_amdgcn_rcpf(t + 1.f);
}

#define MFMA(a, b, c) __builtin_amdgcn_mfma_f32_16x16x32_bf16(a, b, c, 0, 0, 0)

// ---------------------------------------------------------------------------
// Swizzle prepass: fp32 weights -> bf16 MFMA-B fragment order
// frag[nt][ks][lane][8]: n = nt*16 + (lane&15), k = ks*32 + (lane>>4)*8 + j.
// ---------------------------------------------------------------------------
__global__ __launch_bounds__(64) void swz_all(
    const float* __restrict__ Vs, const float* __restrict__ Cs,
    const float* __restrict__ Us, const float* __restrict__ gw,
    us* __restrict__ Vf, us* __restrict__ Cf,
    us* __restrict__ Uf, us* __restrict__ Gf)
{
    int b = blockIdx.x;
    int lane = threadIdx.x;
    if (b < 768) {                       // V: [3][16 nt][16 ks]
        int i = b >> 8, t = b & 255;
        int nt = t >> 4, ks = t & 15;
        int n  = nt * 16 + (lane & 15);
        int k0 = ks * 32 + (lane >> 4) * 8;
        const float* src = Vs + (size_t)i * ELD * DIM + (size_t)n * DIM + k0;
        us* dst = Vf + (size_t)i * ELD * DIM
                + ((size_t)(nt * 16 + ks) * 64 + lane) * 8;
        #pragma unroll
        for (int j = 0; j < 8; ++j) dst[j] = f2bf(src[j]);
    } else if (b < 1536) {               // U': [3][32 nt][8 ks], k = e*64+l
        int bb = b - 768;
        int i = bb >> 8, t = bb & 255;
        int nt = t >> 3, ks = t & 7;
        int n  = nt * 16 + (lane & 15);            // d
        int k0 = ks * 32 + (lane >> 4) * 8;        // e*64 + l
        int e = k0 >> 6, l0 = k0 & 63;
        const float* src = Us + (size_t)i * ENUM * DIM * LR
                         + (size_t)e * DIM * LR + (size_t)n * LR + l0;
        us* dst = Uf + (size_t)i * DIM * ELD
                + ((size_t)(nt * 8 + ks) * 64 + lane) * 8;
        #pragma unroll
        for (int j = 0; j < 8; ++j) dst[j] = f2bf(src[j]);
    } else if (b < 1632) {               // C: [3][4 e][4 nt][2 ks]
        int bb = b - 1536;
        int i = bb >> 5, rest = bb & 31;
        int e = rest >> 3, t = rest & 7;
        int nt = t >> 1, ks = t & 1;
        int n  = nt * 16 + (lane & 15);
        int k0 = ks * 32 + (lane >> 4) * 8;
        const float* src = Cs + (((size_t)(i * ENUM + e) * LR + n) * LR) + k0;
        us* dst = Cf + (size_t)i * ENUM * LR * LR
                + ((size_t)((e * 4 + nt) * 2 + ks) * 64 + lane) * 8;
        #pragma unroll
        for (int j = 0; j < 8; ++j) dst[j] = f2bf(src[j]);
    } else {                             // gate: [16 ks], n<4 real, rest 0
        int ks = b - 1632;
        int n  = lane & 15;
        int k0 = ks * 32 + (lane >> 4) * 8;
        us* dst = Gf + ((size_t)ks * 64 + lane) * 8;
        #pragma unroll
        for (int j = 0; j < 8; ++j)
            dst[j] = (n < ENUM) ? f2bf(gw[(size_t)(k0 + j) * ENUM + n]) : (us)0;
    }
}

// ---------------------------------------------------------------------------
// Fused 3-layer kernel. Block: 16 rows, 512 threads (8 waves), 4 blocks/CU.
// Thread element ownership (16x16x32 D-layout):
//   row = quad*4 + r,  col(G3) = wave*64 + nt*16 + nl.
// G1: wave owns cols [wave*32,+32) (nt_r=2); wave 0 additionally folds the
// gate GEMM in as one extra B-fragment. G2: expert e = wave>>1, col-half
// h = wave&1. G3: wave owns cols [wave*64,+64) (nt_r=4), processed in two
// 32-col halves to keep acc pressure low.
// ---------------------------------------------------------------------------
__global__ __launch_bounds__(NTHR, 8) void dcn_fused(
    const float* __restrict__ x,
    float* __restrict__ out,
    const us* __restrict__ Vf,
    const us* __restrict__ Cf,
    const us* __restrict__ Uf,
    const us* __restrict__ Gf,
    const float* __restrict__ bias)
{
    __shared__ us xl_s[BT * XL_W];       // x_l master, bf16 (16.6 KB)
    __shared__ us y_s[BT * Y_W];         // Y then z (8.4 KB)
    __shared__ float g_s[BT * ENUM];     // gate scores (0.25 KB)

    const int tid  = threadIdx.x;
    const int wave = tid >> 6, lane = tid & 63;
    const int quad = lane >> 4, nl = lane & 15;
    const int row0 = blockIdx.x * BT;

    // ---- stage x -> xl_s (bf16): 16*128 = 2048 float4s, 4 per thread
    #pragma unroll
    for (int it = 0; it < 4; ++it) {
        int f4 = tid + it * NTHR;            // 0..2047
        int r = f4 >> 7, c4 = f4 & 127;
        float4 v = *reinterpret_cast<const float4*>(
            x + (size_t)(row0 + r) * DIM + c4 * 4);
        us4 p;
        p[0] = f2bf(v.x); p[1] = f2bf(v.y); p[2] = f2bf(v.z); p[3] = f2bf(v.w);
        *reinterpret_cast<us4*>(&xl_s[r * XL_W + c4 * 4]) = p;
    }
    __syncthreads();

    // ---- x0 packed bf16 in regs (thread's ownership elements)
    unsigned int x0p[4][2];
    #pragma unroll
    for (int nt = 0; nt < 4; ++nt) {
        int rb = quad * 4;
        int col = wave * 64 + nt * 16 + nl;
        unsigned int b0 = xl_s[(rb + 0) * XL_W + col];
        unsigned int b1 = xl_s[(rb + 1) * XL_W + col];
        unsigned int b2 = xl_s[(rb + 2) * XL_W + col];
        unsigned int b3 = xl_s[(rb + 3) * XL_W + col];
        x0p[nt][0] = b0 | (b1 << 16);
        x0p[nt][1] = b2 | (b3 << 16);
    }

    #pragma unroll 1
    for (int layer = 0; layer < CROSS; ++layer) {
        const us* Vl = Vf + (size_t)layer * ELD * DIM;
        const us* Cl = Cf + (size_t)layer * ENUM * LR * LR;
        const us* Ul = Uf + (size_t)layer * DIM * ELD;
        const float* bl = bias + layer * DIM;

        // ---- GEMM1: Y = tanh(xl @ V^T), wave cols [wave*32,+32); wave 0: gate
        f32x4 acc1[2];
        f32x4 gacc;
        gacc = (f32x4)0.f;
        acc1[0] = (f32x4)0.f;
        acc1[1] = (f32x4)0.f;
        #pragma unroll 4
        for (int ks = 0; ks < 16; ++ks) {
            bf16x8 a = *reinterpret_cast<const bf16x8*>(
                &xl_s[nl * XL_W + ks * 32 + quad * 8]);
            #pragma unroll
            for (int nt = 0; nt < 2; ++nt) {
                bf16x8 bfr = *reinterpret_cast<const bf16x8*>(
                    &Vl[((size_t)((wave * 2 + nt) * 16 + ks) * 64 + lane) * 8]);
                acc1[nt] = MFMA(a, bfr, acc1[nt]);
            }
            if (wave == 0) {
                bf16x8 bg = *reinterpret_cast<const bf16x8*>(
                    &Gf[((size_t)ks * 64 + lane) * 8]);
                gacc = MFMA(a, bg, gacc);
            }
        }
        #pragma unroll
        for (int r = 0; r < 4; ++r) {
            int row = quad * 4 + r;
            #pragma unroll
            for (int nt = 0; nt < 2; ++nt)
                y_s[row * Y_W + wave * 32 + nt * 16 + nl] =
                    f2bf(tanh_fast(acc1[nt][r]));
        }
        if (wave == 0 && nl < ENUM) {
            #pragma unroll
            for (int r = 0; r < 4; ++r)
                g_s[(quad * 4 + r) * ENUM + nl] = gacc[r];
        }
        __syncthreads();

        // ---- GEMM2: z = g ⊙ tanh(Y_e @ C_e^T). e = wave>>1, half = wave&1.
        const int e = wave >> 1, h = wave & 1;
        f32x4 acc2[2];
        acc2[0] = (f32x4)0.f;
        acc2[1] = (f32x4)0.f;
        #pragma unroll
        for (int ks = 0; ks < 2; ++ks) {
            bf16x8 a = *reinterpret_cast<const bf16x8*>(
                &y_s[nl * Y_W + e * 64 + ks * 32 + quad * 8]);
            #pragma unroll
            for (int nt = 0; nt < 2; ++nt) {
                bf16x8 bfr = *reinterpret_cast<const bf16x8*>(
                    &Cl[((size_t)((e * 4 + h * 2 + nt) * 2 + ks) * 64 + lane) * 8]);
                acc2[nt] = MFMA(a, bfr, acc2[nt]);
            }
        }
        __syncthreads();   // all Y reads complete before in-place overwrite
        #pragma unroll
        for (int r = 0; r < 4; ++r) {
            int row = quad * 4 + r;
            float gv = g_s[row * ENUM + e];
            #pragma unroll
            for (int nt = 0; nt < 2; ++nt)
                y_s[row * Y_W + e * 64 + h * 32 + nt * 16 + nl] =
                    f2bf(tanh_fast(acc2[nt][r]) * gv);
        }
        __syncthreads();

        // ---- Gv = sum_e g[row][e]
        float Gv[4];
        #pragma unroll
        for (int r = 0; r < 4; ++r) {
            int row = quad * 4 + r;
            f32x4 g4 = *reinterpret_cast<const f32x4*>(&g_s[row * ENUM]);
            Gv[r] = g4[0] + g4[1] + g4[2] + g4[3];
        }

        // ---- GEMM3: core = z @ U'^T, wave cols [wave*64,+64), K=256.
        // Two 32-col halves to keep acc pressure low.
        #pragma unroll 1
        for (int h3 = 0; h3 < 2; ++h3) {
            float bc[2];
            bc[0] = bl[wave * 64 + h3 * 32 + nl];
            bc[1] = bl[wave * 64 + h3 * 32 + 16 + nl];
            f32x4 acc3[2];
            acc3[0] = (f32x4)0.f;
            acc3[1] = (f32x4)0.f;
            #pragma unroll 2
            for (int ks = 0; ks < 8; ++ks) {
                bf16x8 a = *reinterpret_cast<const bf16x8*>(
                    &y_s[nl * Y_W + ks * 32 + quad * 8]);
                #pragma unroll
                for (int nt = 0; nt < 2; ++nt) {
                    bf16x8 bfr = *reinterpret_cast<const bf16x8*>(
                        &Ul[((size_t)((wave * 4 + h3 * 2 + nt) * 8 + ks) * 64
                             + lane) * 8]);
                    acc3[nt] = MFMA(a, bfr, acc3[nt]);
                }
            }

            // ---- epilogue (this half): xl = xl + x0 * (core + bias*G)
            #pragma unroll
            for (int nt = 0; nt < 2; ++nt) {
                int col = wave * 64 + h3 * 32 + nt * 16 + nl;
                #pragma unroll
                for (int r = 0; r < 4; ++r) {
                    int row = quad * 4 + r;
                    float x0v = bf2f((us)(
                        x0p[h3 * 2 + nt][r >> 1] >> ((r & 1) * 16)));
                    float xlo = bf2f(xl_s[row * XL_W + col]);
                    float res = xlo
                              + x0v * (acc3[nt][r] + bc[nt] * Gv[r]);
                    if (layer == CROSS - 1)
                        out[(size_t)(row0 + row) * DIM + col] = res;
                    else
                        xl_s[row * XL_W + col] = f2bf(res);
                }
            }
        }
        if (layer < CROSS - 1) __syncthreads();
    }
}

// ---------------------------------------------------------------------------
extern "C" void kernel_launch(void* const* d_in, const int* in_sizes, int n_in,
                              void* d_out, int out_size, void* d_ws,
                              size_t ws_size, hipStream_t stream) {
    const float* x      = (const float*)d_in[0];
    const float* Vs     = (const float*)d_in[1];
    const float* Cs     = (const float*)d_in[2];
    const float* Us     = (const float*)d_in[3];
    const float* bias   = (const float*)d_in[4];
    const float* gate_w = (const float*)d_in[5];
    float* out = (float*)d_out;

    us* Vf = (us*)d_ws;                                   // 393216 bf16
    us* Uf = Vf + (size_t)CROSS * ELD * DIM;              // 393216
    us* Cf = Uf + (size_t)CROSS * DIM * ELD;              // 49152
    us* Gf = Cf + (size_t)CROSS * ENUM * LR * LR;         // 8192

    swz_all<<<1648, 64, 0, stream>>>(Vs, Cs, Us, gate_w, Vf, Cf, Uf, Gf);
    dcn_fused<<<BATCH / BT, NTHR, 0, stream>>>(x, out, Vf, Cf, Uf, Gf, bias);
}